// Round 1
// baseline (3916.174 us; speedup 1.0000x reference)
//
#include <hip/hip_runtime.h>

#define NB 8
#define NP 2048
#define KNN 20
#define EPSF 1e-6f

// ---------------- transpose input: x [B,N,3] -> xT [B,3,N] ----------------
__global__ __launch_bounds__(256) void k_transpose_in(const float* __restrict__ x,
                                                      float* __restrict__ xT) {
  int e = blockIdx.x * 256 + threadIdx.x;
  if (e >= NB * 3 * NP) return;
  int n = e % NP;
  int r = e / NP;
  int d = r % 3;
  int b = r / 3;
  xT[e] = x[((long)b * NP + n) * 3 + d];
}

// ---------------- pairwise neg squared distance --------------------------
// X: [B][D3][N] (channel-major, batch stride SB). nd: [B][N][N]
__global__ __launch_bounds__(256) void k_knn_dist(const float* __restrict__ X, long SB, int D3,
                                                  float* __restrict__ nd) {
  int b = blockIdx.z;
  int i0 = blockIdx.y * 32, j0 = blockIdx.x * 32;
  int tx = threadIdx.x;  // 0..31 (col within tile / n index for loads)
  int ty = threadIdx.y;  // 0..7
  const float* Xb = X + (long)b * SB;
  __shared__ float SI[32][33], SJ[32][33];
  float acc0 = 0.f, acc1 = 0.f, acc2 = 0.f, acc3 = 0.f;
  for (int dc = 0; dc < D3; dc += 32) {
    int dcnt = min(32, D3 - dc);
    for (int dd = ty; dd < 32; dd += 8) {
      float vi = 0.f, vj = 0.f;
      if (dd < dcnt) {
        vi = Xb[(long)(dc + dd) * NP + i0 + tx];
        vj = Xb[(long)(dc + dd) * NP + j0 + tx];
      }
      SI[tx][dd] = vi;
      SJ[tx][dd] = vj;
    }
    __syncthreads();
    for (int dd = 0; dd < dcnt; ++dd) {
      float xj = SJ[tx][dd];
      float d0 = SI[ty][dd] - xj;      acc0 -= d0 * d0;
      float d1 = SI[ty + 8][dd] - xj;  acc1 -= d1 * d1;
      float d2 = SI[ty + 16][dd] - xj; acc2 -= d2 * d2;
      float d3 = SI[ty + 24][dd] - xj; acc3 -= d3 * d3;
    }
    __syncthreads();
  }
  float* o = nd + ((long)b * NP + i0) * NP + j0 + tx;
  o[(long)ty * NP] = acc0;
  o[(long)(ty + 8) * NP] = acc1;
  o[(long)(ty + 16) * NP] = acc2;
  o[(long)(ty + 24) * NP] = acc3;
}

// ---------------- top-k (k=20), ties -> lower index (matches lax.top_k) ---
__global__ __launch_bounds__(256) void k_topk(const float* __restrict__ nd,
                                              int* __restrict__ idx) {
  long row = blockIdx.x;  // b*N + i
  const float* r = nd + row * NP;
  __shared__ float vals[NP];
  __shared__ float bv[4];
  __shared__ int bi[4];
  int t = threadIdx.x;
  for (int j = t; j < NP; j += 256) vals[j] = r[j];
  __syncthreads();
  for (int s = 0; s < KNN; ++s) {
    float best = -3.4e38f;
    int besti = NP;
    for (int j = t; j < NP; j += 256) {
      float v = vals[j];
      if (v > best) { best = v; besti = j; }  // ascending j: equal keeps lower idx
    }
    for (int off = 32; off >= 1; off >>= 1) {
      float ov = __shfl_down(best, off);
      int oi = __shfl_down(besti, off);
      if (ov > best || (ov == best && oi < besti)) { best = ov; besti = oi; }
    }
    if ((t & 63) == 0) { bv[t >> 6] = best; bi[t >> 6] = besti; }
    __syncthreads();
    if (t == 0) {
      for (int w = 1; w < 4; ++w)
        if (bv[w] > best || (bv[w] == best && bi[w] < besti)) { best = bv[w]; besti = bi[w]; }
      idx[row * KNN + s] = besti;
      vals[besti] = -3.4e38f;
    }
    __syncthreads();
  }
}

// ---------------- build concatenated weights [Wa; Wb-Wa; Da; Db-Da] -------
__global__ __launch_bounds__(256) void k_wcat(const float* __restrict__ W,
                                              const float* __restrict__ Dm, int C, int Co,
                                              float* __restrict__ Wc) {
  int tot = 4 * Co * C;
  for (int e = blockIdx.x * 256 + threadIdx.x; e < tot; e += gridDim.x * 256) {
    int c = e % C;
    int rr = e / C;
    int g = rr / Co;
    int co = rr % Co;
    const float* M = (g < 2) ? W : Dm;
    long base = (long)co * 2 * C;
    float v = (g & 1) ? (M[base + C + c] - M[base + c]) : M[base + c];
    Wc[e] = v;
  }
}

// ---------------- per-point GEMM: U[b][n][r][d] = sum_c Wc[r][c] X[b][c][d][n]
__global__ __launch_bounds__(256) void k_gemm_u(const float* __restrict__ X, long SB, int C,
                                                const float* __restrict__ Wc, int R4,
                                                float* __restrict__ U) {
  int b = blockIdx.y;
  int n0 = blockIdx.x * 64;
  int tn = threadIdx.x & 63, tr = threadIdx.x >> 6;
  extern __shared__ float XS[];  // [3C][64]
  const float* Xb = X + (long)b * SB;
  int tot = 3 * C * 64;
  for (int e = threadIdx.x; e < tot; e += 256) {
    int nn = e & 63, rest = e >> 6;
    XS[e] = Xb[(long)rest * NP + n0 + nn];
  }
  __syncthreads();
  float* Ub = U + ((long)b * NP + n0 + tn) * R4 * 3;
  for (int rr = tr; rr < R4; rr += 4) {
    const float* wr = Wc + (long)rr * C;
    float a0 = 0.f, a1 = 0.f, a2 = 0.f;
    for (int c = 0; c < C; ++c) {
      float w = wr[c];
      a0 += w * XS[(c * 3 + 0) * 64 + tn];
      a1 += w * XS[(c * 3 + 1) * 64 + tn];
      a2 += w * XS[(c * 3 + 2) * 64 + tn];
    }
    float* up = Ub + rr * 3;
    up[0] = a0; up[1] = a1; up[2] = a2;
  }
}

// ---------------- edge aggregate (gather + VN-LeakyReLU + mean over k) ----
// U rows: [0,Co): Wa*x ; [Co,2Co): (Wb-Wa)*x ; [2Co,3Co): Da*x ; [3Co,4Co): (Db-Da)*x
__global__ __launch_bounds__(256) void k_edge(const float* __restrict__ U, int R4, int Co,
                                              const int* __restrict__ idx,
                                              float* __restrict__ out, long SBo) {
  int pt = blockIdx.x * 4 + (threadIdx.x >> 6);
  int lane = threadIdx.x & 63;
  int b = pt >> 11, n = pt & (NP - 1);
  const int* ip = idx + (long)pt * KNN;
  const float* Un = U + (long)pt * R4 * 3;
  int co0 = lane, co1 = lane + 64;
  bool h0 = co0 < Co, h1 = co1 < Co;
  float cp00 = 0, cp01 = 0, cp02 = 0, cd00 = 0, cd01 = 0, cd02 = 0;
  float cp10 = 0, cp11 = 0, cp12 = 0, cd10 = 0, cd11 = 0, cd12 = 0;
  if (h0) {
    cp00 = Un[(Co + co0) * 3 + 0]; cp01 = Un[(Co + co0) * 3 + 1]; cp02 = Un[(Co + co0) * 3 + 2];
    cd00 = Un[(3 * Co + co0) * 3 + 0]; cd01 = Un[(3 * Co + co0) * 3 + 1]; cd02 = Un[(3 * Co + co0) * 3 + 2];
  }
  if (h1) {
    cp10 = Un[(Co + co1) * 3 + 0]; cp11 = Un[(Co + co1) * 3 + 1]; cp12 = Un[(Co + co1) * 3 + 2];
    cd10 = Un[(3 * Co + co1) * 3 + 0]; cd11 = Un[(3 * Co + co1) * 3 + 1]; cd12 = Un[(3 * Co + co1) * 3 + 2];
  }
  float a00 = 0, a01 = 0, a02 = 0, a10 = 0, a11 = 0, a12 = 0;
  for (int kk = 0; kk < KNN; ++kk) {
    int j = ip[kk];
    const float* Uj = U + ((long)b * NP + j) * R4 * 3;
    if (h0) {
      float p0 = Uj[co0 * 3 + 0] + cp00, p1 = Uj[co0 * 3 + 1] + cp01, p2 = Uj[co0 * 3 + 2] + cp02;
      float q0 = Uj[(2 * Co + co0) * 3 + 0] + cd00, q1 = Uj[(2 * Co + co0) * 3 + 1] + cd01,
            q2 = Uj[(2 * Co + co0) * 3 + 2] + cd02;
      float dot = p0 * q0 + p1 * q1 + p2 * q2;
      float dsq = q0 * q0 + q1 * q1 + q2 * q2;
      float coef = dot < 0.f ? 0.8f * dot / (dsq + EPSF) : 0.f;
      a00 += p0 - coef * q0; a01 += p1 - coef * q1; a02 += p2 - coef * q2;
    }
    if (h1) {
      float p0 = Uj[co1 * 3 + 0] + cp10, p1 = Uj[co1 * 3 + 1] + cp11, p2 = Uj[co1 * 3 + 2] + cp12;
      float q0 = Uj[(2 * Co + co1) * 3 + 0] + cd10, q1 = Uj[(2 * Co + co1) * 3 + 1] + cd11,
            q2 = Uj[(2 * Co + co1) * 3 + 2] + cd12;
      float dot = p0 * q0 + p1 * q1 + p2 * q2;
      float dsq = q0 * q0 + q1 * q1 + q2 * q2;
      float coef = dot < 0.f ? 0.8f * dot / (dsq + EPSF) : 0.f;
      a10 += p0 - coef * q0; a11 += p1 - coef * q1; a12 += p2 - coef * q2;
    }
  }
  const float s = 1.f / KNN;
  if (h0) {
    float* o = out + (long)b * SBo + (long)co0 * 3 * NP + n;
    o[0] = a00 * s; o[NP] = a01 * s; o[2 * NP] = a02 * s;
  }
  if (h1) {
    float* o = out + (long)b * SBo + (long)co1 * 3 * NP + n;
    o[0] = a10 * s; o[NP] = a11 * s; o[2 * NP] = a12 * s;
  }
}

// ---------------- VN linear + VN-LeakyReLU (used for W5, Ws1, Ws2) --------
// X: [B][Cmain][3][N] + optional mean channels (Ci-Cmain, broadcast over n)
__global__ __launch_bounds__(256) void k_vnlin(const float* __restrict__ X, long SBx, int Cmain,
                                               const float* __restrict__ meanp, int Ci,
                                               const float* __restrict__ W,
                                               const float* __restrict__ Dm, int Cd, int Co,
                                               float* __restrict__ Y, long SBy) {
  __shared__ float SX[64 * 3 * 32];
  __shared__ float SW[32 * 64];
  __shared__ float SD[32 * 64];
  int tn = threadIdx.x & 31, tg = threadIdx.x >> 5;
  int n0 = blockIdx.x * 32, co0 = blockIdx.y * 32, b = blockIdx.z;
  const float* Xb = X + (long)b * SBx;
  int Cmean = Ci - Cmain;
  float accp[4][3] = {{0.f, 0.f, 0.f}, {0.f, 0.f, 0.f}, {0.f, 0.f, 0.f}, {0.f, 0.f, 0.f}};
  float accd[4][3] = {{0.f, 0.f, 0.f}, {0.f, 0.f, 0.f}, {0.f, 0.f, 0.f}, {0.f, 0.f, 0.f}};
  for (int dc = 0; dc < Ci; dc += 64) {
    for (int e = threadIdx.x; e < 64 * 3 * 32; e += 256) {
      int tnn = e & 31;
      int rest = e >> 5;  // cc*3 + d
      int cc = rest / 3, d = rest - cc * 3;
      int cg = dc + cc;
      float v = 0.f;
      if (cg < Cmain)
        v = Xb[(long)cg * 3 * NP + (long)d * NP + n0 + tnn];
      else if (cg < Ci)
        v = meanp[((long)b * Cmean + (cg - Cmain)) * 3 + d];
      SX[e] = v;
    }
    for (int e = threadIdx.x; e < 32 * 64; e += 256) {
      int cc = e & 63, col = e >> 6;
      int co = co0 + col, cg = dc + cc;
      SW[e] = (co < Co && cg < Ci) ? W[(long)co * Ci + cg] : 0.f;
    }
    if (Cd > 1) {
      for (int e = threadIdx.x; e < 32 * 64; e += 256) {
        int cc = e & 63, col = e >> 6;
        int co = co0 + col, cg = dc + cc;
        SD[e] = (co < Cd && cg < Ci) ? Dm[(long)co * Ci + cg] : 0.f;
      }
    } else {
      for (int e = threadIdx.x; e < 64; e += 256) {
        int cg = dc + e;
        SD[e] = (cg < Ci) ? Dm[cg] : 0.f;
      }
    }
    __syncthreads();
    if (Cd > 1) {
      for (int cc = 0; cc < 64; ++cc) {
        float x0 = SX[(cc * 3 + 0) * 32 + tn];
        float x1 = SX[(cc * 3 + 1) * 32 + tn];
        float x2 = SX[(cc * 3 + 2) * 32 + tn];
#pragma unroll
        for (int q = 0; q < 4; ++q) {
          float w = SW[(tg * 4 + q) * 64 + cc];
          accp[q][0] += w * x0; accp[q][1] += w * x1; accp[q][2] += w * x2;
          float wd = SD[(tg * 4 + q) * 64 + cc];
          accd[q][0] += wd * x0; accd[q][1] += wd * x1; accd[q][2] += wd * x2;
        }
      }
    } else {
      for (int cc = 0; cc < 64; ++cc) {
        float x0 = SX[(cc * 3 + 0) * 32 + tn];
        float x1 = SX[(cc * 3 + 1) * 32 + tn];
        float x2 = SX[(cc * 3 + 2) * 32 + tn];
        float wd = SD[cc];
        accd[0][0] += wd * x0; accd[0][1] += wd * x1; accd[0][2] += wd * x2;
#pragma unroll
        for (int q = 0; q < 4; ++q) {
          float w = SW[(tg * 4 + q) * 64 + cc];
          accp[q][0] += w * x0; accp[q][1] += w * x1; accp[q][2] += w * x2;
        }
      }
    }
    __syncthreads();
  }
  int n = n0 + tn;
#pragma unroll
  for (int q = 0; q < 4; ++q) {
    int co = co0 + tg * 4 + q;
    if (co < Co) {
      float d0, d1, d2;
      if (Cd > 1) { d0 = accd[q][0]; d1 = accd[q][1]; d2 = accd[q][2]; }
      else        { d0 = accd[0][0]; d1 = accd[0][1]; d2 = accd[0][2]; }
      float p0 = accp[q][0], p1 = accp[q][1], p2 = accp[q][2];
      float dot = p0 * d0 + p1 * d1 + p2 * d2;
      float dsq = d0 * d0 + d1 * d1 + d2 * d2;
      float coef = dot < 0.f ? 0.8f * dot / (dsq + EPSF) : 0.f;
      float* yb = Y + (long)b * SBy + (long)co * 3 * NP + n;
      yb[0] = p0 - coef * d0;
      yb[NP] = p1 - coef * d1;
      yb[2 * NP] = p2 - coef * d2;
    }
  }
}

// ---------------- row means of x5 -----------------------------------------
__global__ __launch_bounds__(256) void k_mean(const float* __restrict__ X,
                                              float* __restrict__ M) {
  long row = blockIdx.x;  // over B*341*3
  const float* xr = X + row * (long)NP;
  float s = 0.f;
  for (int n = threadIdx.x; n < NP; n += 256) s += xr[n];
  __shared__ float red[256];
  red[threadIdx.x] = s;
  __syncthreads();
  for (int st = 128; st > 0; st >>= 1) {
    if (threadIdx.x < st) red[threadIdx.x] += red[threadIdx.x + st];
    __syncthreads();
  }
  if (threadIdx.x == 0) M[row] = red[0] * (1.f / NP);
}

// ---------------- final: fold W6*(xc2*z0) = (W6*xc2)*z0, VN-lrelu, mean ----
__global__ __launch_bounds__(64) void k_final(const float* __restrict__ x5,
                                              const float* __restrict__ x5m,
                                              const float* __restrict__ z2,
                                              const float* __restrict__ Wlin,
                                              const float* __restrict__ W6,
                                              const float* __restrict__ D6,
                                              float* __restrict__ part) {
  int b = blockIdx.x >> 5;  // 32 chunks of 64 points
  int chunk = blockIdx.x & 31;
  int n = chunk * 64 + threadIdx.x;
  __shared__ float W6s[3 * 682];
  __shared__ float D6s[682];
  __shared__ float Wls[3 * 170];
  for (int e = threadIdx.x; e < 3 * 682; e += 64) W6s[e] = W6[e];
  for (int e = threadIdx.x; e < 682; e += 64) D6s[e] = D6[e];
  for (int e = threadIdx.x; e < 3 * 170; e += 64) Wls[e] = Wlin[e];
  __syncthreads();
  const float* x5b = x5 + (long)b * 341 * 3 * NP;
  const float* z2b = z2 + (long)b * 170 * 3 * NP;
  const float* mb = x5m + (long)b * 341 * 3;
  float G00 = 0, G01 = 0, G02 = 0, G10 = 0, G11 = 0, G12 = 0, G20 = 0, G21 = 0, G22 = 0;
  float H0 = 0, H1 = 0, H2 = 0;
  for (int i = 0; i < 682; ++i) {
    float v0, v1, v2;
    if (i < 341) {
      const float* p = x5b + (long)i * 3 * NP + n;
      v0 = p[0]; v1 = p[NP]; v2 = p[2 * NP];
    } else {
      const float* p = mb + (i - 341) * 3;
      v0 = p[0]; v1 = p[1]; v2 = p[2];
    }
    float w0 = W6s[i], w1 = W6s[682 + i], w2 = W6s[2 * 682 + i];
    G00 += w0 * v0; G01 += w0 * v1; G02 += w0 * v2;
    G10 += w1 * v0; G11 += w1 * v1; G12 += w1 * v2;
    G20 += w2 * v0; G21 += w2 * v1; G22 += w2 * v2;
    float wd = D6s[i];
    H0 += wd * v0; H1 += wd * v1; H2 += wd * v2;
  }
  // Z[j][kk] = sum_c Wlin[kk][c] * z2[c][j][n]
  float Z00 = 0, Z01 = 0, Z02 = 0, Z10 = 0, Z11 = 0, Z12 = 0, Z20 = 0, Z21 = 0, Z22 = 0;
  for (int c = 0; c < 170; ++c) {
    const float* p = z2b + (long)c * 3 * NP + n;
    float u0 = p[0], u1 = p[NP], u2 = p[2 * NP];
    float w0 = Wls[c], w1 = Wls[170 + c], w2 = Wls[2 * 170 + c];
    Z00 += w0 * u0; Z10 += w0 * u1; Z20 += w0 * u2;
    Z01 += w1 * u0; Z11 += w1 * u1; Z21 += w1 * u2;
    Z02 += w2 * u0; Z12 += w2 * u1; Z22 += w2 * u2;
  }
  float dv0 = H0 * Z00 + H1 * Z10 + H2 * Z20;
  float dv1 = H0 * Z01 + H1 * Z11 + H2 * Z21;
  float dv2 = H0 * Z02 + H1 * Z12 + H2 * Z22;
  float dsq = dv0 * dv0 + dv1 * dv1 + dv2 * dv2;
  float res[9];
  {
    float Gr[3][3] = {{G00, G01, G02}, {G10, G11, G12}, {G20, G21, G22}};
#pragma unroll
    for (int o = 0; o < 3; ++o) {
      float p0 = Gr[o][0] * Z00 + Gr[o][1] * Z10 + Gr[o][2] * Z20;
      float p1 = Gr[o][0] * Z01 + Gr[o][1] * Z11 + Gr[o][2] * Z21;
      float p2 = Gr[o][0] * Z02 + Gr[o][1] * Z12 + Gr[o][2] * Z22;
      float dot = p0 * dv0 + p1 * dv1 + p2 * dv2;
      float coef = dot < 0.f ? 0.8f * dot / (dsq + EPSF) : 0.f;
      res[o * 3 + 0] = p0 - coef * dv0;
      res[o * 3 + 1] = p1 - coef * dv1;
      res[o * 3 + 2] = p2 - coef * dv2;
    }
  }
#pragma unroll
  for (int e = 0; e < 9; ++e) {
    float v = res[e];
    for (int off = 32; off >= 1; off >>= 1) v += __shfl_down(v, off);
    if (threadIdx.x == 0) part[(long)blockIdx.x * 9 + e] = v;
  }
}

__global__ __launch_bounds__(128) void k_reduce(const float* __restrict__ part,
                                                float* __restrict__ out) {
  int e = threadIdx.x;
  if (e < NB * 9) {
    int b = e / 9, r = e - b * 9;
    float s = 0.f;
    for (int c = 0; c < 32; ++c) s += part[((long)b * 32 + c) * 9 + r];
    out[e] = s * (1.f / NP);
  }
}

// ---------------------------------------------------------------------------
extern "C" void kernel_launch(void* const* d_in, const int* in_sizes, int n_in,
                              void* d_out, int out_size, void* d_ws, size_t ws_size,
                              hipStream_t stream) {
  (void)in_sizes; (void)n_in; (void)out_size;
  const float* x = (const float*)d_in[0];
  const float* W1 = (const float*)d_in[1];
  const float* D1 = (const float*)d_in[2];
  const float* W2 = (const float*)d_in[3];
  const float* D2 = (const float*)d_in[4];
  const float* W3 = (const float*)d_in[5];
  const float* D3w = (const float*)d_in[6];
  const float* W4 = (const float*)d_in[7];
  const float* D4 = (const float*)d_in[8];
  const float* W5 = (const float*)d_in[9];
  const float* D5 = (const float*)d_in[10];
  const float* Ws1 = (const float*)d_in[11];
  const float* Ds1 = (const float*)d_in[12];
  const float* Ws2 = (const float*)d_in[13];
  const float* Ds2 = (const float*)d_in[14];
  const float* Wlin = (const float*)d_in[15];
  const float* W6 = (const float*)d_in[16];
  const float* D6 = (const float*)d_in[17];

  // ---- workspace layout (floats) ----
  const long SBcat = 169L * 3 * NP;
  const long o_xT = 0;                       // 49,152
  const long o_xcat = 49152;                 // 8,306,688
  const long o_idx = 8355840;                // 327,680 ints
  const long o_wcat = 8683520;               // 16,384
  const long o_A = 8699904;                  // U (16,711,680) / x5 (16,760,832)
  const long o_mean = 25460736 + 8192 - 8192;  // = 25,460,736; mean 8,184 floats
  const long o_B = 25468928;                 // nd (33,554,432) / z1+z2
  const long o_z2 = o_B + 16760832;          // 8,355,840
  const long o_part = o_B + 33554432;        // 2,304
  const long total_floats = o_part + 2304;
  if (ws_size < (size_t)total_floats * 4) return;  // insufficient scratch: fail visibly

  float* ws = (float*)d_ws;
  float* xT = ws + o_xT;
  float* xcat = ws + o_xcat;
  int* idx = (int*)(ws + o_idx);
  float* wcat = ws + o_wcat;
  float* Ubuf = ws + o_A;
  float* x5 = ws + o_A;  // alias (U dead after layer 4)
  float* x5m = ws + o_mean;
  float* nd = ws + o_B;
  float* z1 = ws + o_B;  // alias (nd dead after layer-4 top-k)
  float* z2 = ws + o_z2;
  float* part = ws + o_part;

  k_transpose_in<<<(NB * 3 * NP + 255) / 256, 256, 0, stream>>>(x, xT);

  const float* Xl[4] = {xT, xcat, xcat + 21L * 3 * NP, xcat + 42L * 3 * NP};
  long SBl[4] = {3L * NP, SBcat, SBcat, SBcat};
  int Cl[4] = {1, 21, 21, 42};
  int Col[4] = {21, 21, 42, 85};
  int c0l[4] = {0, 21, 42, 84};
  const float* Wl[4] = {W1, W2, W3, W4};
  const float* Dl[4] = {D1, D2, D3w, D4};

  for (int l = 0; l < 4; ++l) {
    int C = Cl[l], Co = Col[l], R4 = 4 * Co, Dd3 = 3 * C;
    k_knn_dist<<<dim3(NP / 32, NP / 32, NB), dim3(32, 8), 0, stream>>>(Xl[l], SBl[l], Dd3, nd);
    k_topk<<<NB * NP, 256, 0, stream>>>(nd, idx);
    k_wcat<<<(4 * Co * C + 255) / 256, 256, 0, stream>>>(Wl[l], Dl[l], C, Co, wcat);
    k_gemm_u<<<dim3(NP / 64, NB), 256, (size_t)C * 3 * 64 * 4, stream>>>(Xl[l], SBl[l], C, wcat,
                                                                         R4, Ubuf);
    k_edge<<<NB * NP / 4, 256, 0, stream>>>(Ubuf, R4, Co, idx, xcat + (long)c0l[l] * 3 * NP,
                                            SBcat);
  }

  // x5 = vn_lrelu(xcat, W5, D5)   [341 <- 169], D has 1 row
  k_vnlin<<<dim3(NP / 32, 11, NB), 256, 0, stream>>>(xcat, SBcat, 169, nullptr, 169, W5, D5, 1,
                                                     341, x5, 341L * 3 * NP);
  k_mean<<<NB * 341 * 3, 256, 0, stream>>>(x5, x5m);
  // z1 = vn_lrelu([x5; mean], Ws1, Ds1)  [341 <- 682]
  k_vnlin<<<dim3(NP / 32, 11, NB), 256, 0, stream>>>(x5, 341L * 3 * NP, 341, x5m, 682, Ws1, Ds1,
                                                     341, 341, z1, 341L * 3 * NP);
  // z2 = vn_lrelu(z1, Ws2, Ds2)  [170 <- 341]
  k_vnlin<<<dim3(NP / 32, 6, NB), 256, 0, stream>>>(z1, 341L * 3 * NP, 341, nullptr, 341, Ws2,
                                                    Ds2, 170, 170, z2, 170L * 3 * NP);
  k_final<<<NB * 32, 64, 0, stream>>>(x5, x5m, z2, Wlin, W6, D6, part);
  k_reduce<<<1, 128, 0, stream>>>(part, (float*)d_out);
}

// Round 2
// 2900.046 us; speedup vs baseline: 1.3504x; 1.3504x over previous
//
#include <hip/hip_runtime.h>

#define NB 8
#define NP 2048
#define KNN 20
#define EPSF 1e-6f

// ---------------- transpose input: x [B,N,3] -> xT [B,3,N] ----------------
__global__ __launch_bounds__(256) void k_transpose_in(const float* __restrict__ x,
                                                      float* __restrict__ xT) {
  int e = blockIdx.x * 256 + threadIdx.x;
  if (e >= NB * 3 * NP) return;
  int n = e % NP;
  int r = e / NP;
  int d = r % 3;
  int b = r / 3;
  xT[e] = x[((long)b * NP + n) * 3 + d];
}

// ---------------- row squared norms: sq[b][n] = sum_d X[d][n]^2 -----------
__global__ __launch_bounds__(256) void k_sqnorm(const float* __restrict__ X, long SB, int D3,
                                                float* __restrict__ sq) {
  int e = blockIdx.x * 256 + threadIdx.x;  // over B*NP
  int b = e >> 11, n = e & (NP - 1);
  const float* Xb = X + (long)b * SB + n;
  float s = 0.f;
  for (int d = 0; d < D3; ++d) {
    float v = Xb[(long)d * NP];
    s += v * v;
  }
  sq[e] = s;
}

// ---------------- pairwise neg squared distance (register-blocked) -------
// nd[b][i][j] = 2*<x_i,x_j> - sq_i - sq_j
__global__ __launch_bounds__(256) void k_knn2(const float* __restrict__ X, long SB, int D3,
                                              const float* __restrict__ sq,
                                              float* __restrict__ nd) {
  __shared__ float SI[32 * 64], SJ[32 * 64];
  int tid = threadIdx.x;
  int ti = tid & 15, tj = tid >> 4;
  int i0 = blockIdx.y * 64, j0 = blockIdx.x * 64, b = blockIdx.z;
  const float* Xb = X + (long)b * SB;
  float acc[4][4];
#pragma unroll
  for (int a = 0; a < 4; ++a)
#pragma unroll
    for (int c = 0; c < 4; ++c) acc[a][c] = 0.f;
  for (int dc = 0; dc < D3; dc += 32) {
    for (int e = tid; e < 32 * 16; e += 256) {
      int ng = e & 15, cc = e >> 4;
      int d = dc + cc;
      float4 vi, vj;
      if (d < D3) {
        vi = ((const float4*)(Xb + (long)d * NP + i0))[ng];
        vj = ((const float4*)(Xb + (long)d * NP + j0))[ng];
      } else {
        vi.x = vi.y = vi.z = vi.w = 0.f;
        vj = vi;
      }
      *(float4*)&SI[cc * 64 + ng * 4] = vi;
      *(float4*)&SJ[cc * 64 + ng * 4] = vj;
    }
    __syncthreads();
    const float4* SIv = (const float4*)SI;
    const float4* SJv = (const float4*)SJ;
    for (int cc = 0; cc < 32; ++cc) {
      float ir[4], jr[4];
      *(float4*)&ir[0] = SIv[cc * 16 + ti];
      *(float4*)&jr[0] = SJv[cc * 16 + tj];
#pragma unroll
      for (int a = 0; a < 4; ++a)
#pragma unroll
        for (int c = 0; c < 4; ++c) acc[a][c] += ir[a] * jr[c];
    }
    __syncthreads();
  }
  const float* sqb = sq + (long)b * NP;
  float sjr[4];
  *(float4*)&sjr[0] = *(const float4*)&sqb[j0 + tj * 4];
#pragma unroll
  for (int a = 0; a < 4; ++a) {
    int i = i0 + ti * 4 + a;
    float si = sqb[i];
    float o[4];
#pragma unroll
    for (int c = 0; c < 4; ++c) o[c] = 2.f * acc[a][c] - si - sjr[c];
    *(float4*)&nd[((long)b * NP + i) * NP + j0 + tj * 4] = *(float4*)&o[0];
  }
}

// ---------------- top-k (k=20), one wave per row, regs-resident ----------
// ties -> lower index (matches lax.top_k); removal-free predicate scan
__global__ __launch_bounds__(256) void k_topk2(const float* __restrict__ nd,
                                               int* __restrict__ idx) {
  int wid = threadIdx.x >> 6, lane = threadIdx.x & 63;
  long row = (long)blockIdx.x * 4 + wid;
  const float4* r4 = (const float4*)(nd + row * NP);
  float vr[32];
#pragma unroll
  for (int m = 0; m < 8; ++m) *(float4*)&vr[m * 4] = r4[m * 64 + lane];
  int lane4 = lane * 4;
  float vl = 3.4e38f;
  int il = -1;
  int* op = idx + row * KNN;
  for (int s = 0; s < KNN; ++s) {
    float bm = -3.4e38f;
    int bi = 1 << 30;
#pragma unroll
    for (int m = 0; m < 8; ++m) {
#pragma unroll
      for (int c = 0; c < 4; ++c) {
        float val = vr[m * 4 + c];
        int j = m * 256 + lane4 + c;
        bool live = (val < vl) || (val == vl && j > il);
        bool better = (val > bm) || (val == bm && j < bi);
        if (live && better) { bm = val; bi = j; }
      }
    }
    for (int off = 32; off >= 1; off >>= 1) {
      float ov = __shfl_xor(bm, off);
      int oi = __shfl_xor(bi, off);
      if (ov > bm || (ov == bm && oi < bi)) { bm = ov; bi = oi; }
    }
    if (lane == 0) op[s] = bi;
    vl = bm;
    il = bi;
  }
}

// ---------------- build concatenated weights [Wa; Wb-Wa; Da; Db-Da] -------
__global__ __launch_bounds__(256) void k_wcat(const float* __restrict__ W,
                                              const float* __restrict__ Dm, int C, int Co,
                                              float* __restrict__ Wc) {
  int tot = 4 * Co * C;
  for (int e = blockIdx.x * 256 + threadIdx.x; e < tot; e += gridDim.x * 256) {
    int c = e % C;
    int rr = e / C;
    int g = rr / Co;
    int co = rr % Co;
    const float* M = (g < 2) ? W : Dm;
    long base = (long)co * 2 * C;
    float v = (g & 1) ? (M[base + C + c] - M[base + c]) : M[base + c];
    Wc[e] = v;
  }
}

// ---------------- per-point GEMM: U[b][n][r][d] = sum_c Wc[r][c] X[b][c][d][n]
__global__ __launch_bounds__(256) void k_gemm_u(const float* __restrict__ X, long SB, int C,
                                                const float* __restrict__ Wc, int R4,
                                                float* __restrict__ U) {
  int b = blockIdx.y;
  int n0 = blockIdx.x * 64;
  int tn = threadIdx.x & 63, tr = threadIdx.x >> 6;
  extern __shared__ float XS[];  // [3C][64]
  const float* Xb = X + (long)b * SB;
  int tot = 3 * C * 64;
  for (int e = threadIdx.x; e < tot; e += 256) {
    int nn = e & 63, rest = e >> 6;
    XS[e] = Xb[(long)rest * NP + n0 + nn];
  }
  __syncthreads();
  float* Ub = U + ((long)b * NP + n0 + tn) * R4 * 3;
  for (int rr = tr; rr < R4; rr += 4) {
    const float* wr = Wc + (long)rr * C;
    float a0 = 0.f, a1 = 0.f, a2 = 0.f;
    for (int c = 0; c < C; ++c) {
      float w = wr[c];
      a0 += w * XS[(c * 3 + 0) * 64 + tn];
      a1 += w * XS[(c * 3 + 1) * 64 + tn];
      a2 += w * XS[(c * 3 + 2) * 64 + tn];
    }
    float* up = Ub + rr * 3;
    up[0] = a0; up[1] = a1; up[2] = a2;
  }
}

// ---------------- edge aggregate (gather + VN-LeakyReLU + mean over k) ----
__global__ __launch_bounds__(256) void k_edge(const float* __restrict__ U, int R4, int Co,
                                              const int* __restrict__ idx,
                                              float* __restrict__ out, long SBo) {
  int pt = blockIdx.x * 4 + (threadIdx.x >> 6);
  int lane = threadIdx.x & 63;
  int b = pt >> 11, n = pt & (NP - 1);
  const int* ip = idx + (long)pt * KNN;
  const float* Un = U + (long)pt * R4 * 3;
  int co0 = lane, co1 = lane + 64;
  bool h0 = co0 < Co, h1 = co1 < Co;
  float cp00 = 0, cp01 = 0, cp02 = 0, cd00 = 0, cd01 = 0, cd02 = 0;
  float cp10 = 0, cp11 = 0, cp12 = 0, cd10 = 0, cd11 = 0, cd12 = 0;
  if (h0) {
    cp00 = Un[(Co + co0) * 3 + 0]; cp01 = Un[(Co + co0) * 3 + 1]; cp02 = Un[(Co + co0) * 3 + 2];
    cd00 = Un[(3 * Co + co0) * 3 + 0]; cd01 = Un[(3 * Co + co0) * 3 + 1]; cd02 = Un[(3 * Co + co0) * 3 + 2];
  }
  if (h1) {
    cp10 = Un[(Co + co1) * 3 + 0]; cp11 = Un[(Co + co1) * 3 + 1]; cp12 = Un[(Co + co1) * 3 + 2];
    cd10 = Un[(3 * Co + co1) * 3 + 0]; cd11 = Un[(3 * Co + co1) * 3 + 1]; cd12 = Un[(3 * Co + co1) * 3 + 2];
  }
  float a00 = 0, a01 = 0, a02 = 0, a10 = 0, a11 = 0, a12 = 0;
  for (int kk = 0; kk < KNN; ++kk) {
    int j = ip[kk];
    const float* Uj = U + ((long)b * NP + j) * R4 * 3;
    if (h0) {
      float p0 = Uj[co0 * 3 + 0] + cp00, p1 = Uj[co0 * 3 + 1] + cp01, p2 = Uj[co0 * 3 + 2] + cp02;
      float q0 = Uj[(2 * Co + co0) * 3 + 0] + cd00, q1 = Uj[(2 * Co + co0) * 3 + 1] + cd01,
            q2 = Uj[(2 * Co + co0) * 3 + 2] + cd02;
      float dot = p0 * q0 + p1 * q1 + p2 * q2;
      float dsq = q0 * q0 + q1 * q1 + q2 * q2;
      float coef = dot < 0.f ? 0.8f * dot / (dsq + EPSF) : 0.f;
      a00 += p0 - coef * q0; a01 += p1 - coef * q1; a02 += p2 - coef * q2;
    }
    if (h1) {
      float p0 = Uj[co1 * 3 + 0] + cp10, p1 = Uj[co1 * 3 + 1] + cp11, p2 = Uj[co1 * 3 + 2] + cp12;
      float q0 = Uj[(2 * Co + co1) * 3 + 0] + cd10, q1 = Uj[(2 * Co + co1) * 3 + 1] + cd11,
            q2 = Uj[(2 * Co + co1) * 3 + 2] + cd12;
      float dot = p0 * q0 + p1 * q1 + p2 * q2;
      float dsq = q0 * q0 + q1 * q1 + q2 * q2;
      float coef = dot < 0.f ? 0.8f * dot / (dsq + EPSF) : 0.f;
      a10 += p0 - coef * q0; a11 += p1 - coef * q1; a12 += p2 - coef * q2;
    }
  }
  const float s = 1.f / KNN;
  if (h0) {
    float* o = out + (long)b * SBo + (long)co0 * 3 * NP + n;
    o[0] = a00 * s; o[NP] = a01 * s; o[2 * NP] = a02 * s;
  }
  if (h1) {
    float* o = out + (long)b * SBo + (long)co1 * 3 * NP + n;
    o[0] = a10 * s; o[NP] = a11 * s; o[2 * NP] = a12 * s;
  }
}

// ---------------- weight transpose (zero-padded): W[Co][Ci] -> WT[CIP][COP]
__global__ __launch_bounds__(256) void k_wT(const float* __restrict__ W, int Co, int Ci,
                                            int COP, int total, float* __restrict__ WT) {
  int e = blockIdx.x * 256 + threadIdx.x;
  if (e >= total) return;
  int ci = e / COP, co = e - ci * COP;
  WT[e] = (co < Co && ci < Ci) ? W[(long)co * Ci + ci] : 0.f;
}

__global__ __launch_bounds__(256) void k_dT1(const float* __restrict__ Dm, int Ci, int CIP,
                                             float* __restrict__ DT) {
  int e = blockIdx.x * 256 + threadIdx.x;
  if (e < CIP) DT[e] = (e < Ci) ? Dm[e] : 0.f;
}

// ---------------- VN linear + VN-LeakyReLU (register-blocked) -------------
// X: [B][Cmain][3][N]; mean channels broadcast; WT/DT: [CIP][COP] transposed
__global__ __launch_bounds__(256, 3) void k_vnlin2(const float* __restrict__ X, long SBx,
                                                   int Cmain, const float* __restrict__ meanp,
                                                   int Ci, int CIP,
                                                   const float* __restrict__ WT,
                                                   const float* __restrict__ DT, int Cd1,
                                                   int Co, int COP, float* __restrict__ Y,
                                                   long SBy) {
  __shared__ float SX[32 * 3 * 64];
  __shared__ float SW[32 * 64];
  __shared__ float SD[32 * 64];
  int tid = threadIdx.x;
  int tn = tid & 15, tc = tid >> 4;
  int n0 = blockIdx.x * 64, co0 = blockIdx.y * 64, b = blockIdx.z;
  const float* Xb = X + (long)b * SBx;
  int Cmean = Ci - Cmain;
  float accp[4][3][4];
  float accd[4][3][4];
#pragma unroll
  for (int i = 0; i < 4; ++i)
#pragma unroll
    for (int d = 0; d < 3; ++d)
#pragma unroll
      for (int j = 0; j < 4; ++j) { accp[i][d][j] = 0.f; accd[i][d][j] = 0.f; }
  for (int dc = 0; dc < CIP; dc += 32) {
    for (int e = tid; e < 32 * 3 * 16; e += 256) {
      int ng = e & 15;
      int rest = e >> 4;
      int cc = rest / 3;
      int d = rest - cc * 3;
      int cg = dc + cc;
      float4 val;
      if (cg < Cmain) {
        val = ((const float4*)(Xb + (long)cg * 3 * NP + (long)d * NP + n0))[ng];
      } else if (cg < Ci) {
        float m = meanp[((long)b * Cmean + (cg - Cmain)) * 3 + d];
        val.x = val.y = val.z = val.w = m;
      } else {
        val.x = val.y = val.z = val.w = 0.f;
      }
      *(float4*)&SX[(cc * 3 + d) * 64 + ng * 4] = val;
    }
    for (int e = tid; e < 32 * 16; e += 256) {
      int cog = e & 15, cc = e >> 4;
      float4 w = ((const float4*)(WT + (long)(dc + cc) * COP + co0))[cog];
      *(float4*)&SW[cc * 64 + cog * 4] = w;
    }
    if (Cd1) {
      if (tid < 32) SD[tid] = DT[dc + tid];
    } else {
      for (int e = tid; e < 32 * 16; e += 256) {
        int cog = e & 15, cc = e >> 4;
        float4 w = ((const float4*)(DT + (long)(dc + cc) * COP + co0))[cog];
        *(float4*)&SD[cc * 64 + cog * 4] = w;
      }
    }
    __syncthreads();
    const float4* SXv = (const float4*)SX;
    const float4* SWv = (const float4*)SW;
    const float4* SDv = (const float4*)SD;
    if (Cd1) {
      for (int cc = 0; cc < 32; ++cc) {
        float xr[12], wr[4];
        *(float4*)&xr[0] = SXv[(cc * 3 + 0) * 16 + tn];
        *(float4*)&xr[4] = SXv[(cc * 3 + 1) * 16 + tn];
        *(float4*)&xr[8] = SXv[(cc * 3 + 2) * 16 + tn];
        *(float4*)&wr[0] = SWv[cc * 16 + tc];
        float ds = SD[cc];
#pragma unroll
        for (int d = 0; d < 3; ++d)
#pragma unroll
          for (int j = 0; j < 4; ++j) accd[0][d][j] += ds * xr[d * 4 + j];
#pragma unroll
        for (int i = 0; i < 4; ++i) {
          float w = wr[i];
#pragma unroll
          for (int d = 0; d < 3; ++d)
#pragma unroll
            for (int j = 0; j < 4; ++j) accp[i][d][j] += w * xr[d * 4 + j];
        }
      }
    } else {
      for (int cc = 0; cc < 32; ++cc) {
        float xr[12], wr[4], dr[4];
        *(float4*)&xr[0] = SXv[(cc * 3 + 0) * 16 + tn];
        *(float4*)&xr[4] = SXv[(cc * 3 + 1) * 16 + tn];
        *(float4*)&xr[8] = SXv[(cc * 3 + 2) * 16 + tn];
        *(float4*)&wr[0] = SWv[cc * 16 + tc];
        *(float4*)&dr[0] = SDv[cc * 16 + tc];
#pragma unroll
        for (int i = 0; i < 4; ++i) {
          float w = wr[i], dd = dr[i];
#pragma unroll
          for (int d = 0; d < 3; ++d)
#pragma unroll
            for (int j = 0; j < 4; ++j) {
              accp[i][d][j] += w * xr[d * 4 + j];
              accd[i][d][j] += dd * xr[d * 4 + j];
            }
        }
      }
    }
    __syncthreads();
  }
  int n = n0 + tn * 4;
#pragma unroll
  for (int i = 0; i < 4; ++i) {
    int co = co0 + tc * 4 + i;
    if (co < Co) {
      float out[3][4];
#pragma unroll
      for (int j = 0; j < 4; ++j) {
        float p0 = accp[i][0][j], p1 = accp[i][1][j], p2 = accp[i][2][j];
        float d0, d1, d2;
        if (Cd1) { d0 = accd[0][0][j]; d1 = accd[0][1][j]; d2 = accd[0][2][j]; }
        else     { d0 = accd[i][0][j]; d1 = accd[i][1][j]; d2 = accd[i][2][j]; }
        float dot = p0 * d0 + p1 * d1 + p2 * d2;
        float dsq = d0 * d0 + d1 * d1 + d2 * d2;
        float coef = dot < 0.f ? 0.8f * dot / (dsq + EPSF) : 0.f;
        out[0][j] = p0 - coef * d0;
        out[1][j] = p1 - coef * d1;
        out[2][j] = p2 - coef * d2;
      }
      float* yb = Y + (long)b * SBy + (long)co * 3 * NP + n;
      *(float4*)&yb[0] = *(float4*)&out[0][0];
      *(float4*)&yb[NP] = *(float4*)&out[1][0];
      *(float4*)&yb[2 * NP] = *(float4*)&out[2][0];
    }
  }
}

// ---------------- row means of x5 -----------------------------------------
__global__ __launch_bounds__(256) void k_mean(const float* __restrict__ X,
                                              float* __restrict__ M) {
  long row = blockIdx.x;  // over B*341*3
  const float* xr = X + row * (long)NP;
  float s = 0.f;
  for (int n = threadIdx.x; n < NP; n += 256) s += xr[n];
  __shared__ float red[256];
  red[threadIdx.x] = s;
  __syncthreads();
  for (int st = 128; st > 0; st >>= 1) {
    if (threadIdx.x < st) red[threadIdx.x] += red[threadIdx.x + st];
    __syncthreads();
  }
  if (threadIdx.x == 0) M[row] = red[0] * (1.f / NP);
}

// ---------------- final: fold W6*(xc2*z0) = (W6*xc2)*z0, VN-lrelu, mean ----
__global__ __launch_bounds__(64) void k_final(const float* __restrict__ x5,
                                              const float* __restrict__ x5m,
                                              const float* __restrict__ z2,
                                              const float* __restrict__ Wlin,
                                              const float* __restrict__ W6,
                                              const float* __restrict__ D6,
                                              float* __restrict__ part) {
  int b = blockIdx.x >> 5;  // 32 chunks of 64 points
  int chunk = blockIdx.x & 31;
  int n = chunk * 64 + threadIdx.x;
  __shared__ float W6s[3 * 682];
  __shared__ float D6s[682];
  __shared__ float Wls[3 * 170];
  for (int e = threadIdx.x; e < 3 * 682; e += 64) W6s[e] = W6[e];
  for (int e = threadIdx.x; e < 682; e += 64) D6s[e] = D6[e];
  for (int e = threadIdx.x; e < 3 * 170; e += 64) Wls[e] = Wlin[e];
  __syncthreads();
  const float* x5b = x5 + (long)b * 341 * 3 * NP;
  const float* z2b = z2 + (long)b * 170 * 3 * NP;
  const float* mb = x5m + (long)b * 341 * 3;
  float G00 = 0, G01 = 0, G02 = 0, G10 = 0, G11 = 0, G12 = 0, G20 = 0, G21 = 0, G22 = 0;
  float H0 = 0, H1 = 0, H2 = 0;
  for (int i = 0; i < 682; ++i) {
    float v0, v1, v2;
    if (i < 341) {
      const float* p = x5b + (long)i * 3 * NP + n;
      v0 = p[0]; v1 = p[NP]; v2 = p[2 * NP];
    } else {
      const float* p = mb + (i - 341) * 3;
      v0 = p[0]; v1 = p[1]; v2 = p[2];
    }
    float w0 = W6s[i], w1 = W6s[682 + i], w2 = W6s[2 * 682 + i];
    G00 += w0 * v0; G01 += w0 * v1; G02 += w0 * v2;
    G10 += w1 * v0; G11 += w1 * v1; G12 += w1 * v2;
    G20 += w2 * v0; G21 += w2 * v1; G22 += w2 * v2;
    float wd = D6s[i];
    H0 += wd * v0; H1 += wd * v1; H2 += wd * v2;
  }
  float Z00 = 0, Z01 = 0, Z02 = 0, Z10 = 0, Z11 = 0, Z12 = 0, Z20 = 0, Z21 = 0, Z22 = 0;
  for (int c = 0; c < 170; ++c) {
    const float* p = z2b + (long)c * 3 * NP + n;
    float u0 = p[0], u1 = p[NP], u2 = p[2 * NP];
    float w0 = Wls[c], w1 = Wls[170 + c], w2 = Wls[2 * 170 + c];
    Z00 += w0 * u0; Z10 += w0 * u1; Z20 += w0 * u2;
    Z01 += w1 * u0; Z11 += w1 * u1; Z21 += w1 * u2;
    Z02 += w2 * u0; Z12 += w2 * u1; Z22 += w2 * u2;
  }
  float dv0 = H0 * Z00 + H1 * Z10 + H2 * Z20;
  float dv1 = H0 * Z01 + H1 * Z11 + H2 * Z21;
  float dv2 = H0 * Z02 + H1 * Z12 + H2 * Z22;
  float dsq = dv0 * dv0 + dv1 * dv1 + dv2 * dv2;
  float res[9];
  {
    float Gr[3][3] = {{G00, G01, G02}, {G10, G11, G12}, {G20, G21, G22}};
#pragma unroll
    for (int o = 0; o < 3; ++o) {
      float p0 = Gr[o][0] * Z00 + Gr[o][1] * Z10 + Gr[o][2] * Z20;
      float p1 = Gr[o][0] * Z01 + Gr[o][1] * Z11 + Gr[o][2] * Z21;
      float p2 = Gr[o][0] * Z02 + Gr[o][1] * Z12 + Gr[o][2] * Z22;
      float dot = p0 * dv0 + p1 * dv1 + p2 * dv2;
      float coef = dot < 0.f ? 0.8f * dot / (dsq + EPSF) : 0.f;
      res[o * 3 + 0] = p0 - coef * dv0;
      res[o * 3 + 1] = p1 - coef * dv1;
      res[o * 3 + 2] = p2 - coef * dv2;
    }
  }
#pragma unroll
  for (int e = 0; e < 9; ++e) {
    float v = res[e];
    for (int off = 32; off >= 1; off >>= 1) v += __shfl_down(v, off);
    if (threadIdx.x == 0) part[(long)blockIdx.x * 9 + e] = v;
  }
}

__global__ __launch_bounds__(128) void k_reduce(const float* __restrict__ part,
                                                float* __restrict__ out) {
  int e = threadIdx.x;
  if (e < NB * 9) {
    int b = e / 9, r = e - b * 9;
    float s = 0.f;
    for (int c = 0; c < 32; ++c) s += part[((long)b * 32 + c) * 9 + r];
    out[e] = s * (1.f / NP);
  }
}

// ---------------------------------------------------------------------------
extern "C" void kernel_launch(void* const* d_in, const int* in_sizes, int n_in,
                              void* d_out, int out_size, void* d_ws, size_t ws_size,
                              hipStream_t stream) {
  (void)in_sizes; (void)n_in; (void)out_size;
  const float* x = (const float*)d_in[0];
  const float* W1 = (const float*)d_in[1];
  const float* D1 = (const float*)d_in[2];
  const float* W2 = (const float*)d_in[3];
  const float* D2 = (const float*)d_in[4];
  const float* W3 = (const float*)d_in[5];
  const float* D3w = (const float*)d_in[6];
  const float* W4 = (const float*)d_in[7];
  const float* D4 = (const float*)d_in[8];
  const float* W5 = (const float*)d_in[9];
  const float* D5 = (const float*)d_in[10];
  const float* Ws1 = (const float*)d_in[11];
  const float* Ds1 = (const float*)d_in[12];
  const float* Ws2 = (const float*)d_in[13];
  const float* Ds2 = (const float*)d_in[14];
  const float* Wlin = (const float*)d_in[15];
  const float* W6 = (const float*)d_in[16];
  const float* D6 = (const float*)d_in[17];

  // ---- workspace layout (floats) ----
  const long SBcat = 169L * 3 * NP;
  const long o_xT = 0;
  const long o_xcat = 49152;
  const long o_idx = o_xcat + 8306688;   // 8,355,840
  const long o_wcat = o_idx + 327680;    // 8,683,520 (also reused for `part`)
  const long o_sq = o_wcat + 32768;      // 8,716,288
  const long o_A = o_sq + 16384;         // 8,732,672 : U / x5
  const long o_mean = o_A + 16760832;    // 25,493,504
  const long o_B = o_mean + 8192;        // 25,501,696 : nd / z1+z2+WT
  const long o_z2 = o_B + 16760832;
  const long o_WT = o_B + 25116672;      // after z2, inside dead-nd region
  const long a_W5T = o_WT;               // 192*384 = 73,728
  const long a_D5T = a_W5T + 73728;      // 256
  const long a_Ws1T = a_D5T + 256;       // 704*384 = 270,336
  const long a_Ds1T = a_Ws1T + 270336;
  const long a_Ws2T = a_Ds1T + 270336;   // 352*192 = 67,584
  const long a_Ds2T = a_Ws2T + 67584;
  const long total_floats = o_B + 33554432;  // 59,056,128
  if (ws_size < (size_t)total_floats * 4) return;

  float* ws = (float*)d_ws;
  float* xT = ws + o_xT;
  float* xcat = ws + o_xcat;
  int* idx = (int*)(ws + o_idx);
  float* wcat = ws + o_wcat;
  float* part = ws + o_wcat;  // alias: wcat dead after layer loop
  float* sq = ws + o_sq;
  float* Ubuf = ws + o_A;
  float* x5 = ws + o_A;  // alias (U dead after layer 4)
  float* x5m = ws + o_mean;
  float* nd = ws + o_B;
  float* z1 = ws + o_B;  // alias (nd dead after layer-4 top-k)
  float* z2 = ws + o_z2;

  k_transpose_in<<<(NB * 3 * NP + 255) / 256, 256, 0, stream>>>(x, xT);

  const float* Xl[4] = {xT, xcat, xcat + 21L * 3 * NP, xcat + 42L * 3 * NP};
  long SBl[4] = {3L * NP, SBcat, SBcat, SBcat};
  int Cl[4] = {1, 21, 21, 42};
  int Col[4] = {21, 21, 42, 85};
  int c0l[4] = {0, 21, 42, 84};
  const float* Wl[4] = {W1, W2, W3, W4};
  const float* Dl[4] = {D1, D2, D3w, D4};

  for (int l = 0; l < 4; ++l) {
    int C = Cl[l], Co = Col[l], R4 = 4 * Co, Dd3 = 3 * C;
    k_sqnorm<<<NB * NP / 256, 256, 0, stream>>>(Xl[l], SBl[l], Dd3, sq);
    k_knn2<<<dim3(NP / 64, NP / 64, NB), 256, 0, stream>>>(Xl[l], SBl[l], Dd3, sq, nd);
    k_topk2<<<NB * NP / 4, 256, 0, stream>>>(nd, idx);
    k_wcat<<<(4 * Co * C + 255) / 256, 256, 0, stream>>>(Wl[l], Dl[l], C, Co, wcat);
    k_gemm_u<<<dim3(NP / 64, NB), 256, (size_t)C * 3 * 64 * 4, stream>>>(Xl[l], SBl[l], C, wcat,
                                                                         R4, Ubuf);
    k_edge<<<NB * NP / 4, 256, 0, stream>>>(Ubuf, R4, Co, idx, xcat + (long)c0l[l] * 3 * NP,
                                            SBcat);
  }

  // weight transposes (into dead-nd region)
  k_wT<<<(192 * 384 + 255) / 256, 256, 0, stream>>>(W5, 341, 169, 384, 192 * 384, ws + a_W5T);
  k_dT1<<<1, 256, 0, stream>>>(D5, 169, 192, ws + a_D5T);
  k_wT<<<(704 * 384 + 255) / 256, 256, 0, stream>>>(Ws1, 341, 682, 384, 704 * 384, ws + a_Ws1T);
  k_wT<<<(704 * 384 + 255) / 256, 256, 0, stream>>>(Ds1, 341, 682, 384, 704 * 384, ws + a_Ds1T);
  k_wT<<<(352 * 192 + 255) / 256, 256, 0, stream>>>(Ws2, 170, 341, 192, 352 * 192, ws + a_Ws2T);
  k_wT<<<(352 * 192 + 255) / 256, 256, 0, stream>>>(Ds2, 170, 341, 192, 352 * 192, ws + a_Ds2T);

  // x5 = vn_lrelu(xcat, W5, D5)   [341 <- 169], D has 1 row
  k_vnlin2<<<dim3(NP / 64, 6, NB), 256, 0, stream>>>(xcat, SBcat, 169, nullptr, 169, 192,
                                                     ws + a_W5T, ws + a_D5T, 1, 341, 384, x5,
                                                     341L * 3 * NP);
  k_mean<<<NB * 341 * 3, 256, 0, stream>>>(x5, x5m);
  // z1 = vn_lrelu([x5; mean], Ws1, Ds1)  [341 <- 682]
  k_vnlin2<<<dim3(NP / 64, 6, NB), 256, 0, stream>>>(x5, 341L * 3 * NP, 341, x5m, 682, 704,
                                                     ws + a_Ws1T, ws + a_Ds1T, 0, 341, 384, z1,
                                                     341L * 3 * NP);
  // z2 = vn_lrelu(z1, Ws2, Ds2)  [170 <- 341]
  k_vnlin2<<<dim3(NP / 64, 3, NB), 256, 0, stream>>>(z1, 341L * 3 * NP, 341, nullptr, 341, 352,
                                                     ws + a_Ws2T, ws + a_Ds2T, 0, 170, 192, z2,
                                                     170L * 3 * NP);
  k_final<<<NB * 32, 64, 0, stream>>>(x5, x5m, z2, Wlin, W6, D6, part);
  k_reduce<<<1, 128, 0, stream>>>(part, (float*)d_out);
}

// Round 3
// 2861.335 us; speedup vs baseline: 1.3687x; 1.0135x over previous
//
#include <hip/hip_runtime.h>

#define NB 8
#define NP 2048
#define KNN 20
#define EPSF 1e-6f

// ---------------- transpose input: x [B,N,3] -> xT [B,3,N] ----------------
__global__ __launch_bounds__(256) void k_transpose_in(const float* __restrict__ x,
                                                      float* __restrict__ xT) {
  int e = blockIdx.x * 256 + threadIdx.x;
  if (e >= NB * 3 * NP) return;
  int n = e % NP;
  int r = e / NP;
  int d = r % 3;
  int b = r / 3;
  xT[e] = x[((long)b * NP + n) * 3 + d];
}

// ---------------- row squared norms: sq[b][n] = sum_d X[d][n]^2 -----------
__global__ __launch_bounds__(256) void k_sqnorm(const float* __restrict__ X, long SB, int D3,
                                                float* __restrict__ sq) {
  int e = blockIdx.x * 256 + threadIdx.x;  // over B*NP
  int b = e >> 11, n = e & (NP - 1);
  const float* Xb = X + (long)b * SB + n;
  float s = 0.f;
  for (int d = 0; d < D3; ++d) {
    float v = Xb[(long)d * NP];
    s += v * v;
  }
  sq[e] = s;
}

// ---------------- pairwise neg squared distance (register-blocked) -------
// nd[b][i][j] = 2*<x_i,x_j> - sq_i - sq_j
__global__ __launch_bounds__(256) void k_knn2(const float* __restrict__ X, long SB, int D3,
                                              const float* __restrict__ sq,
                                              float* __restrict__ nd) {
  __shared__ float SI[32 * 64], SJ[32 * 64];
  int tid = threadIdx.x;
  int ti = tid & 15, tj = tid >> 4;
  int i0 = blockIdx.y * 64, j0 = blockIdx.x * 64, b = blockIdx.z;
  const float* Xb = X + (long)b * SB;
  float acc[4][4];
#pragma unroll
  for (int a = 0; a < 4; ++a)
#pragma unroll
    for (int c = 0; c < 4; ++c) acc[a][c] = 0.f;
  for (int dc = 0; dc < D3; dc += 32) {
    for (int e = tid; e < 32 * 16; e += 256) {
      int ng = e & 15, cc = e >> 4;
      int d = dc + cc;
      float4 vi, vj;
      if (d < D3) {
        vi = ((const float4*)(Xb + (long)d * NP + i0))[ng];
        vj = ((const float4*)(Xb + (long)d * NP + j0))[ng];
      } else {
        vi.x = vi.y = vi.z = vi.w = 0.f;
        vj = vi;
      }
      *(float4*)&SI[cc * 64 + ng * 4] = vi;
      *(float4*)&SJ[cc * 64 + ng * 4] = vj;
    }
    __syncthreads();
    const float4* SIv = (const float4*)SI;
    const float4* SJv = (const float4*)SJ;
    for (int cc = 0; cc < 32; ++cc) {
      float ir[4], jr[4];
      *(float4*)&ir[0] = SIv[cc * 16 + ti];
      *(float4*)&jr[0] = SJv[cc * 16 + tj];
#pragma unroll
      for (int a = 0; a < 4; ++a)
#pragma unroll
        for (int c = 0; c < 4; ++c) acc[a][c] += ir[a] * jr[c];
    }
    __syncthreads();
  }
  const float* sqb = sq + (long)b * NP;
  float sjr[4];
  *(float4*)&sjr[0] = *(const float4*)&sqb[j0 + tj * 4];
#pragma unroll
  for (int a = 0; a < 4; ++a) {
    int i = i0 + ti * 4 + a;
    float si = sqb[i];
    float o[4];
#pragma unroll
    for (int c = 0; c < 4; ++c) o[c] = 2.f * acc[a][c] - si - sjr[c];
    *(float4*)&nd[((long)b * NP + i) * NP + j0 + tj * 4] = *(float4*)&o[0];
  }
}

// ---------------- top-k (k=20), one wave per row, regs-resident ----------
__global__ __launch_bounds__(256) void k_topk2(const float* __restrict__ nd,
                                               int* __restrict__ idx) {
  int wid = threadIdx.x >> 6, lane = threadIdx.x & 63;
  long row = (long)blockIdx.x * 4 + wid;
  const float4* r4 = (const float4*)(nd + row * NP);
  float vr[32];
#pragma unroll
  for (int m = 0; m < 8; ++m) *(float4*)&vr[m * 4] = r4[m * 64 + lane];
  int lane4 = lane * 4;
  float vl = 3.4e38f;
  int il = -1;
  int* op = idx + row * KNN;
  for (int s = 0; s < KNN; ++s) {
    float bm = -3.4e38f;
    int bi = 1 << 30;
#pragma unroll
    for (int m = 0; m < 8; ++m) {
#pragma unroll
      for (int c = 0; c < 4; ++c) {
        float val = vr[m * 4 + c];
        int j = m * 256 + lane4 + c;
        bool live = (val < vl) || (val == vl && j > il);
        bool better = (val > bm) || (val == bm && j < bi);
        if (live && better) { bm = val; bi = j; }
      }
    }
    for (int off = 32; off >= 1; off >>= 1) {
      float ov = __shfl_xor(bm, off);
      int oi = __shfl_xor(bi, off);
      if (ov > bm || (ov == bm && oi < bi)) { bm = ov; bi = oi; }
    }
    if (lane == 0) op[s] = bi;
    vl = bm;
    il = bi;
  }
}

// ---------------- build concatenated weights [Wa; Wb-Wa; Da; Db-Da] -------
__global__ __launch_bounds__(256) void k_wcat(const float* __restrict__ W,
                                              const float* __restrict__ Dm, int C, int Co,
                                              float* __restrict__ Wc) {
  int tot = 4 * Co * C;
  for (int e = blockIdx.x * 256 + threadIdx.x; e < tot; e += gridDim.x * 256) {
    int c = e % C;
    int rr = e / C;
    int g = rr / Co;
    int co = rr % Co;
    const float* M = (g < 2) ? W : Dm;
    long base = (long)co * 2 * C;
    float v = (g & 1) ? (M[base + C + c] - M[base + c]) : M[base + c];
    Wc[e] = v;
  }
}

// ---------------- per-point GEMM: U[b][n][r][d] = sum_c Wc[r][c] X[b][c][d][n]
__global__ __launch_bounds__(256) void k_gemm_u(const float* __restrict__ X, long SB, int C,
                                                const float* __restrict__ Wc, int R4,
                                                float* __restrict__ U) {
  int b = blockIdx.y;
  int n0 = blockIdx.x * 64;
  int tn = threadIdx.x & 63, tr = threadIdx.x >> 6;
  extern __shared__ float XS[];  // [3C][64]
  const float* Xb = X + (long)b * SB;
  int tot = 3 * C * 64;
  for (int e = threadIdx.x; e < tot; e += 256) {
    int nn = e & 63, rest = e >> 6;
    XS[e] = Xb[(long)rest * NP + n0 + nn];
  }
  __syncthreads();
  float* Ub = U + ((long)b * NP + n0 + tn) * R4 * 3;
  for (int rr = tr; rr < R4; rr += 4) {
    const float* wr = Wc + (long)rr * C;
    float a0 = 0.f, a1 = 0.f, a2 = 0.f;
    for (int c = 0; c < C; ++c) {
      float w = wr[c];
      a0 += w * XS[(c * 3 + 0) * 64 + tn];
      a1 += w * XS[(c * 3 + 1) * 64 + tn];
      a2 += w * XS[(c * 3 + 2) * 64 + tn];
    }
    float* up = Ub + rr * 3;
    up[0] = a0; up[1] = a1; up[2] = a2;
  }
}

// ---------------- edge aggregate (gather + VN-LeakyReLU + mean over k) ----
__global__ __launch_bounds__(256) void k_edge(const float* __restrict__ U, int R4, int Co,
                                              const int* __restrict__ idx,
                                              float* __restrict__ out, long SBo) {
  int pt = blockIdx.x * 4 + (threadIdx.x >> 6);
  int lane = threadIdx.x & 63;
  int b = pt >> 11, n = pt & (NP - 1);
  const int* ip = idx + (long)pt * KNN;
  const float* Un = U + (long)pt * R4 * 3;
  int co0 = lane, co1 = lane + 64;
  bool h0 = co0 < Co, h1 = co1 < Co;
  float cp00 = 0, cp01 = 0, cp02 = 0, cd00 = 0, cd01 = 0, cd02 = 0;
  float cp10 = 0, cp11 = 0, cp12 = 0, cd10 = 0, cd11 = 0, cd12 = 0;
  if (h0) {
    cp00 = Un[(Co + co0) * 3 + 0]; cp01 = Un[(Co + co0) * 3 + 1]; cp02 = Un[(Co + co0) * 3 + 2];
    cd00 = Un[(3 * Co + co0) * 3 + 0]; cd01 = Un[(3 * Co + co0) * 3 + 1]; cd02 = Un[(3 * Co + co0) * 3 + 2];
  }
  if (h1) {
    cp10 = Un[(Co + co1) * 3 + 0]; cp11 = Un[(Co + co1) * 3 + 1]; cp12 = Un[(Co + co1) * 3 + 2];
    cd10 = Un[(3 * Co + co1) * 3 + 0]; cd11 = Un[(3 * Co + co1) * 3 + 1]; cd12 = Un[(3 * Co + co1) * 3 + 2];
  }
  float a00 = 0, a01 = 0, a02 = 0, a10 = 0, a11 = 0, a12 = 0;
  for (int kk = 0; kk < KNN; ++kk) {
    int j = ip[kk];
    const float* Uj = U + ((long)b * NP + j) * R4 * 3;
    if (h0) {
      float p0 = Uj[co0 * 3 + 0] + cp00, p1 = Uj[co0 * 3 + 1] + cp01, p2 = Uj[co0 * 3 + 2] + cp02;
      float q0 = Uj[(2 * Co + co0) * 3 + 0] + cd00, q1 = Uj[(2 * Co + co0) * 3 + 1] + cd01,
            q2 = Uj[(2 * Co + co0) * 3 + 2] + cd02;
      float dot = p0 * q0 + p1 * q1 + p2 * q2;
      float dsq = q0 * q0 + q1 * q1 + q2 * q2;
      float coef = dot < 0.f ? 0.8f * dot / (dsq + EPSF) : 0.f;
      a00 += p0 - coef * q0; a01 += p1 - coef * q1; a02 += p2 - coef * q2;
    }
    if (h1) {
      float p0 = Uj[co1 * 3 + 0] + cp10, p1 = Uj[co1 * 3 + 1] + cp11, p2 = Uj[co1 * 3 + 2] + cp12;
      float q0 = Uj[(2 * Co + co1) * 3 + 0] + cd10, q1 = Uj[(2 * Co + co1) * 3 + 1] + cd11,
            q2 = Uj[(2 * Co + co1) * 3 + 2] + cd12;
      float dot = p0 * q0 + p1 * q1 + p2 * q2;
      float dsq = q0 * q0 + q1 * q1 + q2 * q2;
      float coef = dot < 0.f ? 0.8f * dot / (dsq + EPSF) : 0.f;
      a10 += p0 - coef * q0; a11 += p1 - coef * q1; a12 += p2 - coef * q2;
    }
  }
  const float s = 1.f / KNN;
  if (h0) {
    float* o = out + (long)b * SBo + (long)co0 * 3 * NP + n;
    o[0] = a00 * s; o[NP] = a01 * s; o[2 * NP] = a02 * s;
  }
  if (h1) {
    float* o = out + (long)b * SBo + (long)co1 * 3 * NP + n;
    o[0] = a10 * s; o[NP] = a11 * s; o[2 * NP] = a12 * s;
  }
}

// ---------------- weight transpose (zero-padded): W[Co][Ci] -> WT[CIP][COP]
__global__ __launch_bounds__(256) void k_wT(const float* __restrict__ W, int Co, int Ci,
                                            int COP, int total, float* __restrict__ WT) {
  int e = blockIdx.x * 256 + threadIdx.x;
  if (e >= total) return;
  int ci = e / COP, co = e - ci * COP;
  WT[e] = (co < Co && ci < Ci) ? W[(long)co * Ci + ci] : 0.f;
}

__global__ __launch_bounds__(256) void k_dT1(const float* __restrict__ Dm, int Ci, int CIP,
                                             float* __restrict__ DT) {
  int e = blockIdx.x * 256 + threadIdx.x;
  if (e < CIP) DT[e] = (e < Ci) ? Dm[e] : 0.f;
}

// ---------------- VN linear + VN-LeakyReLU (register-blocked) -------------
// X: [B][Cmain][3][N]; mean channels broadcast; WT/DT: [CIP][COP] transposed
__global__ __launch_bounds__(256) void k_vnlin2(const float* __restrict__ X, long SBx,
                                                int Cmain, const float* __restrict__ meanp,
                                                int Ci, int CIP,
                                                const float* __restrict__ WT,
                                                const float* __restrict__ DT, int Cd1,
                                                int Co, int COP, float* __restrict__ Y,
                                                long SBy) {
  __shared__ float SX[32 * 3 * 64];
  __shared__ float SW[32 * 64];
  __shared__ float SD[32 * 64];
  int tid = threadIdx.x;
  int tn = tid & 15, tc = tid >> 4;
  int n0 = blockIdx.x * 64, co0 = blockIdx.y * 64, b = blockIdx.z;
  const float* Xb = X + (long)b * SBx;
  int Cmean = Ci - Cmain;
  float accp[4][3][4];
  float accd[4][3][4];
#pragma unroll
  for (int i = 0; i < 4; ++i)
#pragma unroll
    for (int d = 0; d < 3; ++d)
#pragma unroll
      for (int j = 0; j < 4; ++j) { accp[i][d][j] = 0.f; accd[i][d][j] = 0.f; }
  for (int dc = 0; dc < CIP; dc += 32) {
    for (int e = tid; e < 32 * 3 * 16; e += 256) {
      int ng = e & 15;
      int rest = e >> 4;
      int cc = rest / 3;
      int d = rest - cc * 3;
      int cg = dc + cc;
      float4 val;
      if (cg < Cmain) {
        val = ((const float4*)(Xb + (long)cg * 3 * NP + (long)d * NP + n0))[ng];
      } else if (cg < Ci) {
        float m = meanp[((long)b * Cmean + (cg - Cmain)) * 3 + d];
        val.x = val.y = val.z = val.w = m;
      } else {
        val.x = val.y = val.z = val.w = 0.f;
      }
      *(float4*)&SX[(cc * 3 + d) * 64 + ng * 4] = val;
    }
    for (int e = tid; e < 32 * 16; e += 256) {
      int cog = e & 15, cc = e >> 4;
      float4 w = ((const float4*)(WT + (long)(dc + cc) * COP + co0))[cog];
      *(float4*)&SW[cc * 64 + cog * 4] = w;
    }
    if (Cd1) {
      if (tid < 32) SD[tid] = DT[dc + tid];
    } else {
      for (int e = tid; e < 32 * 16; e += 256) {
        int cog = e & 15, cc = e >> 4;
        float4 w = ((const float4*)(DT + (long)(dc + cc) * COP + co0))[cog];
        *(float4*)&SD[cc * 64 + cog * 4] = w;
      }
    }
    __syncthreads();
    const float4* SXv = (const float4*)SX;
    const float4* SWv = (const float4*)SW;
    const float4* SDv = (const float4*)SD;
    if (Cd1) {
      for (int cc = 0; cc < 32; ++cc) {
        float xr[12], wr[4];
        *(float4*)&xr[0] = SXv[(cc * 3 + 0) * 16 + tn];
        *(float4*)&xr[4] = SXv[(cc * 3 + 1) * 16 + tn];
        *(float4*)&xr[8] = SXv[(cc * 3 + 2) * 16 + tn];
        *(float4*)&wr[0] = SWv[cc * 16 + tc];
        float ds = SD[cc];
#pragma unroll
        for (int d = 0; d < 3; ++d)
#pragma unroll
          for (int j = 0; j < 4; ++j) accd[0][d][j] += ds * xr[d * 4 + j];
#pragma unroll
        for (int i = 0; i < 4; ++i) {
          float w = wr[i];
#pragma unroll
          for (int d = 0; d < 3; ++d)
#pragma unroll
            for (int j = 0; j < 4; ++j) accp[i][d][j] += w * xr[d * 4 + j];
        }
      }
    } else {
      for (int cc = 0; cc < 32; ++cc) {
        float xr[12], wr[4], dr[4];
        *(float4*)&xr[0] = SXv[(cc * 3 + 0) * 16 + tn];
        *(float4*)&xr[4] = SXv[(cc * 3 + 1) * 16 + tn];
        *(float4*)&xr[8] = SXv[(cc * 3 + 2) * 16 + tn];
        *(float4*)&wr[0] = SWv[cc * 16 + tc];
        *(float4*)&dr[0] = SDv[cc * 16 + tc];
#pragma unroll
        for (int i = 0; i < 4; ++i) {
          float w = wr[i], dd = dr[i];
#pragma unroll
          for (int d = 0; d < 3; ++d)
#pragma unroll
            for (int j = 0; j < 4; ++j) {
              accp[i][d][j] += w * xr[d * 4 + j];
              accd[i][d][j] += dd * xr[d * 4 + j];
            }
        }
      }
    }
    __syncthreads();
  }
  int n = n0 + tn * 4;
#pragma unroll
  for (int i = 0; i < 4; ++i) {
    int co = co0 + tc * 4 + i;
    if (co < Co) {
      float out[3][4];
#pragma unroll
      for (int j = 0; j < 4; ++j) {
        float p0 = accp[i][0][j], p1 = accp[i][1][j], p2 = accp[i][2][j];
        float d0, d1, d2;
        if (Cd1) { d0 = accd[0][0][j]; d1 = accd[0][1][j]; d2 = accd[0][2][j]; }
        else     { d0 = accd[i][0][j]; d1 = accd[i][1][j]; d2 = accd[i][2][j]; }
        float dot = p0 * d0 + p1 * d1 + p2 * d2;
        float dsq = d0 * d0 + d1 * d1 + d2 * d2;
        float coef = dot < 0.f ? 0.8f * dot / (dsq + EPSF) : 0.f;
        out[0][j] = p0 - coef * d0;
        out[1][j] = p1 - coef * d1;
        out[2][j] = p2 - coef * d2;
      }
      float* yb = Y + (long)b * SBy + (long)co * 3 * NP + n;
      *(float4*)&yb[0] = *(float4*)&out[0][0];
      *(float4*)&yb[NP] = *(float4*)&out[1][0];
      *(float4*)&yb[2 * NP] = *(float4*)&out[2][0];
    }
  }
}

// ---------------- row means of x5 -----------------------------------------
__global__ __launch_bounds__(256) void k_mean(const float* __restrict__ X,
                                              float* __restrict__ M) {
  long row = blockIdx.x;  // over B*341*3
  const float* xr = X + row * (long)NP;
  float s = 0.f;
  for (int n = threadIdx.x; n < NP; n += 256) s += xr[n];
  __shared__ float red[256];
  red[threadIdx.x] = s;
  __syncthreads();
  for (int st = 128; st > 0; st >>= 1) {
    if (threadIdx.x < st) red[threadIdx.x] += red[threadIdx.x + st];
    __syncthreads();
  }
  if (threadIdx.x == 0) M[row] = red[0] * (1.f / NP);
}

// ---------------- final: fold W6*(xc2*z0) = (W6*xc2)*z0, VN-lrelu, mean ----
// 4 waves split the channel loops; LDS partial reduce; epilogue on wave 0.
__global__ __launch_bounds__(256) void k_final(const float* __restrict__ x5,
                                               const float* __restrict__ x5m,
                                               const float* __restrict__ z2,
                                               const float* __restrict__ Wlin,
                                               const float* __restrict__ W6,
                                               const float* __restrict__ D6,
                                               float* __restrict__ part) {
  int b = blockIdx.x >> 5;  // 32 chunks of 64 points
  int chunk = blockIdx.x & 31;
  int w = threadIdx.x >> 6, lane = threadIdx.x & 63;
  int n = chunk * 64 + lane;
  __shared__ float W6s[3 * 682];
  __shared__ float D6s[682];
  __shared__ float Wls[3 * 170];
  __shared__ float red[4][64][22];
  for (int e = threadIdx.x; e < 3 * 682; e += 256) W6s[e] = W6[e];
  for (int e = threadIdx.x; e < 682; e += 256) D6s[e] = D6[e];
  for (int e = threadIdx.x; e < 3 * 170; e += 256) Wls[e] = Wlin[e];
  __syncthreads();
  const float* x5b = x5 + (long)b * 341 * 3 * NP;
  const float* z2b = z2 + (long)b * 170 * 3 * NP;
  const float* mb = x5m + (long)b * 341 * 3;
  float G[9] = {0, 0, 0, 0, 0, 0, 0, 0, 0};
  float H[3] = {0, 0, 0};
  float Z[9] = {0, 0, 0, 0, 0, 0, 0, 0, 0};
  int i0 = w * 171, i1 = min(682, i0 + 171);
  for (int i = i0; i < i1; ++i) {
    float v0, v1, v2;
    if (i < 341) {
      const float* p = x5b + (long)i * 3 * NP + n;
      v0 = p[0]; v1 = p[NP]; v2 = p[2 * NP];
    } else {
      const float* p = mb + (i - 341) * 3;
      v0 = p[0]; v1 = p[1]; v2 = p[2];
    }
    float w0 = W6s[i], w1 = W6s[682 + i], w2 = W6s[2 * 682 + i];
    G[0] += w0 * v0; G[1] += w0 * v1; G[2] += w0 * v2;
    G[3] += w1 * v0; G[4] += w1 * v1; G[5] += w1 * v2;
    G[6] += w2 * v0; G[7] += w2 * v1; G[8] += w2 * v2;
    float wd = D6s[i];
    H[0] += wd * v0; H[1] += wd * v1; H[2] += wd * v2;
  }
  int c0 = w * 43, c1 = min(170, c0 + 43);
  for (int c = c0; c < c1; ++c) {
    const float* p = z2b + (long)c * 3 * NP + n;
    float u0 = p[0], u1 = p[NP], u2 = p[2 * NP];
    float w0 = Wls[c], w1 = Wls[170 + c], w2 = Wls[2 * 170 + c];
    // Z[j*3+k] = sum_c Wls[k*170+c] * u_j
    Z[0] += w0 * u0; Z[3] += w0 * u1; Z[6] += w0 * u2;
    Z[1] += w1 * u0; Z[4] += w1 * u1; Z[7] += w1 * u2;
    Z[2] += w2 * u0; Z[5] += w2 * u1; Z[8] += w2 * u2;
  }
  float* rp = red[w][lane];
#pragma unroll
  for (int q = 0; q < 9; ++q) rp[q] = G[q];
#pragma unroll
  for (int q = 0; q < 3; ++q) rp[9 + q] = H[q];
#pragma unroll
  for (int q = 0; q < 9; ++q) rp[12 + q] = Z[q];
  __syncthreads();
  if (w == 0) {
#pragma unroll
    for (int q = 0; q < 9; ++q) G[q] += red[1][lane][q] + red[2][lane][q] + red[3][lane][q];
#pragma unroll
    for (int q = 0; q < 3; ++q) H[q] += red[1][lane][9 + q] + red[2][lane][9 + q] + red[3][lane][9 + q];
#pragma unroll
    for (int q = 0; q < 9; ++q) Z[q] += red[1][lane][12 + q] + red[2][lane][12 + q] + red[3][lane][12 + q];
    float dv0 = H[0] * Z[0] + H[1] * Z[3] + H[2] * Z[6];
    float dv1 = H[0] * Z[1] + H[1] * Z[4] + H[2] * Z[7];
    float dv2 = H[0] * Z[2] + H[1] * Z[5] + H[2] * Z[8];
    float dsq = dv0 * dv0 + dv1 * dv1 + dv2 * dv2;
    float res[9];
#pragma unroll
    for (int o = 0; o < 3; ++o) {
      float p0 = G[o * 3 + 0] * Z[0] + G[o * 3 + 1] * Z[3] + G[o * 3 + 2] * Z[6];
      float p1 = G[o * 3 + 0] * Z[1] + G[o * 3 + 1] * Z[4] + G[o * 3 + 2] * Z[7];
      float p2 = G[o * 3 + 0] * Z[2] + G[o * 3 + 1] * Z[5] + G[o * 3 + 2] * Z[8];
      float dot = p0 * dv0 + p1 * dv1 + p2 * dv2;
      float coef = dot < 0.f ? 0.8f * dot / (dsq + EPSF) : 0.f;
      res[o * 3 + 0] = p0 - coef * dv0;
      res[o * 3 + 1] = p1 - coef * dv1;
      res[o * 3 + 2] = p2 - coef * dv2;
    }
#pragma unroll
    for (int e = 0; e < 9; ++e) {
      float v = res[e];
      for (int off = 32; off >= 1; off >>= 1) v += __shfl_down(v, off);
      if (lane == 0) part[(long)blockIdx.x * 9 + e] = v;
    }
  }
}

__global__ __launch_bounds__(128) void k_reduce(const float* __restrict__ part,
                                                float* __restrict__ out) {
  int e = threadIdx.x;
  if (e < NB * 9) {
    int b = e / 9, r = e - b * 9;
    float s = 0.f;
    for (int c = 0; c < 32; ++c) s += part[((long)b * 32 + c) * 9 + r];
    out[e] = s * (1.f / NP);
  }
}

// ---------------------------------------------------------------------------
extern "C" void kernel_launch(void* const* d_in, const int* in_sizes, int n_in,
                              void* d_out, int out_size, void* d_ws, size_t ws_size,
                              hipStream_t stream) {
  (void)in_sizes; (void)n_in; (void)out_size;
  const float* x = (const float*)d_in[0];
  const float* W1 = (const float*)d_in[1];
  const float* D1 = (const float*)d_in[2];
  const float* W2 = (const float*)d_in[3];
  const float* D2 = (const float*)d_in[4];
  const float* W3 = (const float*)d_in[5];
  const float* D3w = (const float*)d_in[6];
  const float* W4 = (const float*)d_in[7];
  const float* D4 = (const float*)d_in[8];
  const float* W5 = (const float*)d_in[9];
  const float* D5 = (const float*)d_in[10];
  const float* Ws1 = (const float*)d_in[11];
  const float* Ds1 = (const float*)d_in[12];
  const float* Ws2 = (const float*)d_in[13];
  const float* Ds2 = (const float*)d_in[14];
  const float* Wlin = (const float*)d_in[15];
  const float* W6 = (const float*)d_in[16];
  const float* D6 = (const float*)d_in[17];

  // ---- workspace layout (floats) ----
  const long SBcat = 169L * 3 * NP;
  const long o_xT = 0;
  const long o_xcat = 49152;
  const long o_idx = o_xcat + 8306688;   // 8,355,840
  const long o_wcat = o_idx + 327680;    // 8,683,520 (also reused for `part`)
  const long o_sq = o_wcat + 32768;      // 8,716,288
  const long o_A = o_sq + 16384;         // 8,732,672 : U / x5
  const long o_mean = o_A + 16760832;    // 25,493,504
  const long o_B = o_mean + 8192;        // 25,501,696 : nd / z1+z2+WT
  const long o_z2 = o_B + 16760832;
  const long o_WT = o_B + 25116672;      // after z2, inside dead-nd region
  const long a_W5T = o_WT;               // 192*384 = 73,728
  const long a_D5T = a_W5T + 73728;      // 256
  const long a_Ws1T = a_D5T + 256;       // 704*384 = 270,336
  const long a_Ds1T = a_Ws1T + 270336;
  const long a_Ws2T = a_Ds1T + 270336;   // 352*192 = 67,584
  const long a_Ds2T = a_Ws2T + 67584;
  const long total_floats = o_B + 33554432;  // 59,056,128
  if (ws_size < (size_t)total_floats * 4) return;

  float* ws = (float*)d_ws;
  float* xT = ws + o_xT;
  float* xcat = ws + o_xcat;
  int* idx = (int*)(ws + o_idx);
  float* wcat = ws + o_wcat;
  float* part = ws + o_wcat;  // alias: wcat dead after layer loop
  float* sq = ws + o_sq;
  float* Ubuf = ws + o_A;
  float* x5 = ws + o_A;  // alias (U dead after layer 4)
  float* x5m = ws + o_mean;
  float* nd = ws + o_B;
  float* z1 = ws + o_B;  // alias (nd dead after layer-4 top-k)
  float* z2 = ws + o_z2;

  k_transpose_in<<<(NB * 3 * NP + 255) / 256, 256, 0, stream>>>(x, xT);

  const float* Xl[4] = {xT, xcat, xcat + 21L * 3 * NP, xcat + 42L * 3 * NP};
  long SBl[4] = {3L * NP, SBcat, SBcat, SBcat};
  int Cl[4] = {1, 21, 21, 42};
  int Col[4] = {21, 21, 42, 85};
  int c0l[4] = {0, 21, 42, 84};
  const float* Wl[4] = {W1, W2, W3, W4};
  const float* Dl[4] = {D1, D2, D3w, D4};

  for (int l = 0; l < 4; ++l) {
    int C = Cl[l], Co = Col[l], R4 = 4 * Co, Dd3 = 3 * C;
    k_sqnorm<<<NB * NP / 256, 256, 0, stream>>>(Xl[l], SBl[l], Dd3, sq);
    k_knn2<<<dim3(NP / 64, NP / 64, NB), 256, 0, stream>>>(Xl[l], SBl[l], Dd3, sq, nd);
    k_topk2<<<NB * NP / 4, 256, 0, stream>>>(nd, idx);
    k_wcat<<<(4 * Co * C + 255) / 256, 256, 0, stream>>>(Wl[l], Dl[l], C, Co, wcat);
    k_gemm_u<<<dim3(NP / 64, NB), 256, (size_t)C * 3 * 64 * 4, stream>>>(Xl[l], SBl[l], C, wcat,
                                                                         R4, Ubuf);
    k_edge<<<NB * NP / 4, 256, 0, stream>>>(Ubuf, R4, Co, idx, xcat + (long)c0l[l] * 3 * NP,
                                            SBcat);
  }

  // weight transposes (into dead-nd region)
  k_wT<<<(192 * 384 + 255) / 256, 256, 0, stream>>>(W5, 341, 169, 384, 192 * 384, ws + a_W5T);
  k_dT1<<<1, 256, 0, stream>>>(D5, 169, 192, ws + a_D5T);
  k_wT<<<(704 * 384 + 255) / 256, 256, 0, stream>>>(Ws1, 341, 682, 384, 704 * 384, ws + a_Ws1T);
  k_wT<<<(704 * 384 + 255) / 256, 256, 0, stream>>>(Ds1, 341, 682, 384, 704 * 384, ws + a_Ds1T);
  k_wT<<<(352 * 192 + 255) / 256, 256, 0, stream>>>(Ws2, 170, 341, 192, 352 * 192, ws + a_Ws2T);
  k_wT<<<(352 * 192 + 255) / 256, 256, 0, stream>>>(Ds2, 170, 341, 192, 352 * 192, ws + a_Ds2T);

  // x5 = vn_lrelu(xcat, W5, D5)   [341 <- 169], D has 1 row
  k_vnlin2<<<dim3(NP / 64, 6, NB), 256, 0, stream>>>(xcat, SBcat, 169, nullptr, 169, 192,
                                                     ws + a_W5T, ws + a_D5T, 1, 341, 384, x5,
                                                     341L * 3 * NP);
  k_mean<<<NB * 341 * 3, 256, 0, stream>>>(x5, x5m);
  // z1 = vn_lrelu([x5; mean], Ws1, Ds1)  [341 <- 682]
  k_vnlin2<<<dim3(NP / 64, 6, NB), 256, 0, stream>>>(x5, 341L * 3 * NP, 341, x5m, 682, 704,
                                                     ws + a_Ws1T, ws + a_Ds1T, 0, 341, 384, z1,
                                                     341L * 3 * NP);
  // z2 = vn_lrelu(z1, Ws2, Ds2)  [170 <- 341]
  k_vnlin2<<<dim3(NP / 64, 3, NB), 256, 0, stream>>>(z1, 341L * 3 * NP, 341, nullptr, 341, 352,
                                                     ws + a_Ws2T, ws + a_Ds2T, 0, 170, 192, z2,
                                                     170L * 3 * NP);
  k_final<<<NB * 32, 256, 0, stream>>>(x5, x5m, z2, Wlin, W6, D6, part);
  k_reduce<<<1, 128, 0, stream>>>(part, (float*)d_out);
}